// Round 1
// baseline (563.930 us; speedup 1.0000x reference)
//
#include <hip/hip_runtime.h>

#define C_DIM 128
#define K_CB  1024
#define N_ROWS 131072
#define NUMEL (N_ROWS * C_DIM)   // 16777216
#define BM 64
#define BK 64
#define XPAD 132                 // pad stride (floats) -> conflict-free b128
#define NBLK (N_ROWS / BM)       // 2048

// ---------------- codebook norms ----------------
__global__ void cbnorm_kernel(const float* __restrict__ cb, float* __restrict__ norms) {
    int k = blockIdx.x * 256 + threadIdx.x;
    if (k >= K_CB) return;
    const float4* row = reinterpret_cast<const float4*>(cb) + k * 32;
    float s = 0.f;
    #pragma unroll
    for (int i = 0; i < 32; ++i) {
        float4 v = row[i];
        s += v.x * v.x;
        s += v.y * v.y;
        s += v.z * v.z;
        s += v.w * v.w;
    }
    norms[k] = s;
}

// ---------------- main: distances + argmin + quantize + loss partials ----------------
__launch_bounds__(256, 2)
__global__ void vq_main_kernel(const float* __restrict__ in,
                               const float* __restrict__ cb,
                               const float* __restrict__ norms,
                               float* __restrict__ out_q,
                               float* __restrict__ out_idx,
                               float* __restrict__ partials) {
    __shared__ float xs[BM * XPAD];     // 33792 B
    __shared__ float cbs[BK * XPAD];    // 33792 B
    __shared__ float cbn_s[K_CB];       // 4096 B
    __shared__ int   idx_s[BM];
    __shared__ float red_s[4];

    const int tid = threadIdx.x;
    const int blk = blockIdx.x;
    const int n0  = blk * BM;

    for (int i = tid; i < K_CB; i += 256) cbn_s[i] = norms[i];

    // ---- stage x tile: gather the [B,C,D,H,W] -> [n, c] transpose ----
    // n = b*16384 + (d*1024 + h*32 + w); in offset = b*2097152 + c*16384 + (n & 16383)
    {
        const int base = (n0 >> 14) * (C_DIM * 16384) + (n0 & 16383);
        #pragma unroll
        for (int i = 0; i < 8; ++i) {
            int idx = tid + i * 256;   // 0..2047
            int nl  = idx & 63;
            int c4  = idx >> 6;        // 0..31
            float4 v;
            v.x = in[base + (c4 * 4 + 0) * 16384 + nl];
            v.y = in[base + (c4 * 4 + 1) * 16384 + nl];
            v.z = in[base + (c4 * 4 + 2) * 16384 + nl];
            v.w = in[base + (c4 * 4 + 3) * 16384 + nl];
            *reinterpret_cast<float4*>(&xs[nl * XPAD + c4 * 4]) = v;
        }
    }
    __syncthreads();

    const int tx = tid & 15;
    const int ty = tid >> 4;

    // per-row ||x||^2 (fp32, per-row consistent across lanes)
    float xn[4];
    #pragma unroll
    for (int i = 0; i < 4; ++i) {
        const float* xr = &xs[(ty * 4 + i) * XPAD];
        float s = 0.f;
        #pragma unroll
        for (int c = 0; c < C_DIM; ++c) s += xr[c] * xr[c];
        xn[i] = s;
    }

    float best[4];
    int   bidx[4];
    #pragma unroll
    for (int i = 0; i < 4; ++i) { best[i] = 3.4e38f; bidx[i] = 0; }

    for (int k0 = 0; k0 < K_CB; k0 += BK) {
        __syncthreads();
        // stage codebook tile (contiguous, float4)
        const float4* src = reinterpret_cast<const float4*>(cb) + k0 * 32;
        #pragma unroll
        for (int i = 0; i < 8; ++i) {
            int f4 = tid + i * 256;    // 0..2047
            int kk = f4 >> 5;          // 0..63
            int c4 = f4 & 31;
            float4 v = src[f4];
            *reinterpret_cast<float4*>(&cbs[kk * XPAD + c4 * 4]) = v;
        }
        __syncthreads();

        float dot[4][4];
        #pragma unroll
        for (int i = 0; i < 4; ++i)
            #pragma unroll
            for (int j = 0; j < 4; ++j) dot[i][j] = 0.f;

        #pragma unroll 8
        for (int c = 0; c < C_DIM; c += 4) {
            float4 a[4], b[4];
            #pragma unroll
            for (int i = 0; i < 4; ++i)
                a[i] = *reinterpret_cast<const float4*>(&xs[(ty * 4 + i) * XPAD + c]);
            #pragma unroll
            for (int j = 0; j < 4; ++j)
                b[j] = *reinterpret_cast<const float4*>(&cbs[(tx + 16 * j) * XPAD + c]);
            #pragma unroll
            for (int i = 0; i < 4; ++i)
                #pragma unroll
                for (int j = 0; j < 4; ++j) {
                    dot[i][j] += a[i].x * b[j].x;
                    dot[i][j] += a[i].y * b[j].y;
                    dot[i][j] += a[i].z * b[j].z;
                    dot[i][j] += a[i].w * b[j].w;
                }
        }

        // faithful fp32 scoring: (||x||^2 + ||cb||^2) - 2*dot  (ties -> lowest k)
        #pragma unroll
        for (int j = 0; j < 4; ++j) {
            int k = k0 + tx + 16 * j;
            float bn = cbn_s[k];
            #pragma unroll
            for (int i = 0; i < 4; ++i) {
                float t1 = xn[i] + bn;
                float s  = t1 - 2.0f * dot[i][j];
                if (s < best[i]) { best[i] = s; bidx[i] = k; }  // ascending k per thread
            }
        }
    }

    // reduce argmin across the 16 tx lanes (same wave)
    #pragma unroll
    for (int i = 0; i < 4; ++i) {
        float v = best[i]; int ix = bidx[i];
        #pragma unroll
        for (int m = 1; m < 16; m <<= 1) {
            float ov = __shfl_xor(v, m, 64);
            int   oi = __shfl_xor(ix, m, 64);
            if (ov < v || (ov == v && oi < ix)) { v = ov; ix = oi; }
        }
        if (tx == 0) idx_s[ty * 4 + i] = ix;
    }
    __syncthreads();

    // indices output (as float values)
    if (tid < BM) out_idx[n0 + tid] = (float)idx_s[tid];

    // quantized + straight-through + loss (linear/coalesced; the "bug" makes
    // both quantized and inputs use the same flat offset here)
    float acc = 0.f;
    const float4* cb4 = reinterpret_cast<const float4*>(cb);
    const float4* in4 = reinterpret_cast<const float4*>(in);
    float4* out4 = reinterpret_cast<float4*>(out_q);
    #pragma unroll
    for (int i = 0; i < 8; ++i) {
        int idx = tid + i * 256;      // 0..2047
        int row = idx >> 5;           // 0..63
        int c4  = idx & 31;
        int kq  = idx_s[row];
        float4 q = cb4[kq * 32 + c4];
        float4 x = in4[(n0 + row) * 32 + c4];
        float4 d, o;
        d.x = q.x - x.x; d.y = q.y - x.y; d.z = q.z - x.z; d.w = q.w - x.w;
        o.x = x.x + d.x; o.y = x.y + d.y; o.z = x.z + d.z; o.w = x.w + d.w;
        out4[(n0 + row) * 32 + c4] = o;
        acc += d.x * d.x; acc += d.y * d.y; acc += d.z * d.z; acc += d.w * d.w;
    }

    #pragma unroll
    for (int m = 1; m < 64; m <<= 1) acc += __shfl_xor(acc, m, 64);
    if ((tid & 63) == 0) red_s[tid >> 6] = acc;
    __syncthreads();
    if (tid == 0) partials[blk] = red_s[0] + red_s[1] + red_s[2] + red_s[3];
}

// ---------------- final loss reduce ----------------
__global__ void loss_final_kernel(const float* __restrict__ partials, float* __restrict__ out_loss) {
    __shared__ float red_s[4];
    float s = 0.f;
    for (int i = threadIdx.x; i < NBLK; i += 256) s += partials[i];
    #pragma unroll
    for (int m = 1; m < 64; m <<= 1) s += __shfl_xor(s, m, 64);
    if ((threadIdx.x & 63) == 0) red_s[threadIdx.x >> 6] = s;
    __syncthreads();
    if (threadIdx.x == 0) {
        float tot = red_s[0] + red_s[1] + red_s[2] + red_s[3];
        out_loss[0] = 1.25f * (tot / (float)NUMEL);
    }
}

extern "C" void kernel_launch(void* const* d_in, const int* in_sizes, int n_in,
                              void* d_out, int out_size, void* d_ws, size_t ws_size,
                              hipStream_t stream) {
    (void)in_sizes; (void)n_in; (void)out_size; (void)ws_size;
    const float* in = (const float*)d_in[0];
    const float* cb = (const float*)d_in[1];
    float* out      = (float*)d_out;
    float* norms    = (float*)d_ws;          // 1024 floats
    float* partials = norms + K_CB;          // 2048 floats

    cbnorm_kernel<<<4, 256, 0, stream>>>(cb, norms);
    vq_main_kernel<<<NBLK, 256, 0, stream>>>(in, cb, norms,
                                             out,                 // quantized_st
                                             out + NUMEL + 1,     // indices (after loss scalar)
                                             partials);
    loss_final_kernel<<<1, 256, 0, stream>>>(partials, out + NUMEL);
}